// Round 5
// baseline (1230.385 us; speedup 1.0000x reference)
//
#include <hip/hip_runtime.h>

// LocallyConnected2D: y[n,h,w] = relu(sum_{i,j} x[n,h+i,w+j]*W[h,w,i,j] + b[h,w])
// lane = batch n (N=64=wave). History:
//  R1: weights scalarized (s_load stream) -> lgkmcnt(0) drains. WRITE=65MB (clean).
//  R2: f[12] local array -> scratch spill (WRITE 223MB).
//  R3: global uniform weight loads, no pipeline -> compiler serialized (84 VGPR)
//      + spilled (WRITE 191MB).
//  R4: weights via LDS -> compiler hoisted LDS reads across r-iters, hit 128-VGPR
//      step, STILL spilled (WRITE 190.6MB == R3's excess). Weights have zero
//      cross-wave reuse -> LDS staging pays the bytes twice for nothing.
//  R5: weights as uniform-address VMEM float4 (imm offsets off one base, vzero
//      anti-scalarization), EXPLICIT 1-iteration prefetch pipeline (cur/nxt),
//      asm memory fence per r-iteration to bound hoisting (no spill by
//      construction, ~226 VGPR peak). LDS carries only x (conflict-free).

#define H_IN 512
#define W_IN 512
#define H_OUT 504
#define W_OUT 504
#define W_T 8
#define H_T 4
#define TROWS (H_T + 8)      // 12 staged input rows
#define XF (TROWS * 1024)    // 12288 floats = 48 KB

__launch_bounds__(256, 2)
__global__ void lc2d_kernel(const float* __restrict__ x,
                            const float* __restrict__ weight,
                            const float* __restrict__ bias,
                            float* __restrict__ out) {
    __shared__ float lds[XF];   // x tile only: [row 0..11][cgrp 0..3][n 0..63][4]

    const int t    = threadIdx.x;
    const int lane = t & 63;          // batch index n
    const int wv   = t >> 6;          // wave 0..3

    const int h0 = blockIdx.y * H_T;
    const int w0 = blockIdx.x * W_T;

    // ---- stage x tile (wave wv owns cgrp=wv plane, lane = n; conflict-free) ----
    {
        const float* gsrc = x + (size_t)lane * (H_IN * W_IN)
                              + (size_t)h0 * W_IN + w0 + wv * 4;
        float* ldst = &lds[wv * 256 + lane * 4];
        #pragma unroll
        for (int row = 0; row < TROWS; ++row) {
            const float4 v = *reinterpret_cast<const float4*>(gsrc + row * W_IN);
            *reinterpret_cast<float4*>(ldst + row * 1024) = v;
        }
    }
    __syncthreads();

    const int wvu = __builtin_amdgcn_readfirstlane(wv);
    const int h   = h0 + wvu;                      // this wave's output row

    float acc[W_T];
    {
        const float* bptr = bias + (size_t)h * W_OUT + w0;
        #pragma unroll
        for (int k = 0; k < W_T; ++k) acc[k] = bptr[k];
    }

    // Wave-uniform weight base; vzero keeps it on the VMEM (vector) path.
    // All 24 loads per iteration are immediate offsets (< 4 KB) off this base.
    int vzero;
    asm volatile("v_mov_b32 %0, 0" : "=v"(vzero));
    const float* wchunk = weight + ((size_t)h * W_OUT + w0) * 81 + vzero;

    float4 cur[24], nxt[24];   // constant-indexed only -> registers

    // ---- prologue: load r=0 windows ----
    #pragma unroll
    for (int k = 0; k < 8; ++k) {
        const int astart = (k * 81) & ~3;
        cur[3 * k + 0] = *reinterpret_cast<const float4*>(wchunk + astart);
        cur[3 * k + 1] = *reinterpret_cast<const float4*>(wchunk + astart + 4);
        cur[3 * k + 2] = *reinterpret_cast<const float4*>(wchunk + astart + 8);
    }

    #pragma unroll
    for (int r = 0; r < 9; ++r) {
        // x row (wv + r): 16 floats per lane via 4 conflict-free ds_read_b128
        float xr[16];
        const int lrow = wv + r;
        #pragma unroll
        for (int c = 0; c < 4; ++c) {
            const float4 v = *reinterpret_cast<const float4*>(
                &lds[lrow * 1024 + c * 256 + lane * 4]);
            xr[4 * c + 0] = v.x; xr[4 * c + 1] = v.y;
            xr[4 * c + 2] = v.z; xr[4 * c + 3] = v.w;
        }

        // prefetch next r's weight windows (in flight across this r's FMAs)
        if (r < 8) {
            #pragma unroll
            for (int k = 0; k < 8; ++k) {
                const int astart = (k * 81 + (r + 1) * 9) & ~3;
                nxt[3 * k + 0] = *reinterpret_cast<const float4*>(wchunk + astart);
                nxt[3 * k + 1] = *reinterpret_cast<const float4*>(wchunk + astart + 4);
                nxt[3 * k + 2] = *reinterpret_cast<const float4*>(wchunk + astart + 8);
            }
        }

        #pragma unroll
        for (int k = 0; k < 8; ++k) {
            const int base = k * 81 + r * 9;       // compile-time after unroll
            const int d    = base & 3;             // compile-time shift
            const float4 v0 = cur[3 * k + 0];
            const float4 v1 = cur[3 * k + 1];
            const float4 v2 = cur[3 * k + 2];
            float t0, t1, t2, t3, t4, t5, t6, t7, t8;
            if (d == 0) {
                t0=v0.x; t1=v0.y; t2=v0.z; t3=v0.w; t4=v1.x; t5=v1.y; t6=v1.z; t7=v1.w; t8=v2.x;
            } else if (d == 1) {
                t0=v0.y; t1=v0.z; t2=v0.w; t3=v1.x; t4=v1.y; t5=v1.z; t6=v1.w; t7=v2.x; t8=v2.y;
            } else if (d == 2) {
                t0=v0.z; t1=v0.w; t2=v1.x; t3=v1.y; t4=v1.z; t5=v1.w; t6=v2.x; t7=v2.y; t8=v2.z;
            } else {
                t0=v0.w; t1=v1.x; t2=v1.y; t3=v1.z; t4=v1.w; t5=v2.x; t6=v2.y; t7=v2.z; t8=v2.w;
            }
            acc[k] = fmaf(t0, xr[k + 0], acc[k]);
            acc[k] = fmaf(t1, xr[k + 1], acc[k]);
            acc[k] = fmaf(t2, xr[k + 2], acc[k]);
            acc[k] = fmaf(t3, xr[k + 3], acc[k]);
            acc[k] = fmaf(t4, xr[k + 4], acc[k]);
            acc[k] = fmaf(t5, xr[k + 5], acc[k]);
            acc[k] = fmaf(t6, xr[k + 6], acc[k]);
            acc[k] = fmaf(t7, xr[k + 7], acc[k]);
            acc[k] = fmaf(t8, xr[k + 8], acc[k]);
        }

        if (r < 8) {
            #pragma unroll
            for (int q = 0; q < 24; ++q) cur[q] = nxt[q];  // SSA rename, no movs
        }

        // Bound hoisting to one-iteration lookahead: nothing memory-related
        // from iteration r+1 may move above this point.
        asm volatile("" ::: "memory");
    }

    // ---- epilogue: ReLU + store (1 row x 8 floats per lane, 16B-aligned) ----
    float* o = out + (size_t)lane * (H_OUT * W_OUT) + (size_t)h * W_OUT + w0;
    float4 s;
    s.x = fmaxf(acc[0], 0.f); s.y = fmaxf(acc[1], 0.f);
    s.z = fmaxf(acc[2], 0.f); s.w = fmaxf(acc[3], 0.f);
    *reinterpret_cast<float4*>(o) = s;
    s.x = fmaxf(acc[4], 0.f); s.y = fmaxf(acc[5], 0.f);
    s.z = fmaxf(acc[6], 0.f); s.w = fmaxf(acc[7], 0.f);
    *reinterpret_cast<float4*>(o + 4) = s;
}

extern "C" void kernel_launch(void* const* d_in, const int* in_sizes, int n_in,
                              void* d_out, int out_size, void* d_ws, size_t ws_size,
                              hipStream_t stream) {
    const float* x      = (const float*)d_in[0];
    const float* weight = (const float*)d_in[1];
    const float* bias   = (const float*)d_in[2];
    float* out          = (float*)d_out;

    dim3 grid(W_OUT / W_T, H_OUT / H_T);   // 63 x 126
    dim3 block(256);
    lc2d_kernel<<<grid, block, 0, stream>>>(x, weight, bias, out);
}